// Round 1
// baseline (471.400 us; speedup 1.0000x reference)
//
#include <hip/hip_runtime.h>
#include <stdint.h>

#define B_ 2
#define S_ 2048
#define E_ 2048
#define H_ 16
#define KV_ 4
#define D_ 128
#define G_ (H_ / KV_)
#define M_ (B_ * S_)   // 4096 rows (b*s)

typedef unsigned short u16;
typedef unsigned int u32;
typedef __bf16 bf16x8 __attribute__((ext_vector_type(8)));
typedef float f32x4 __attribute__((ext_vector_type(4)));

__device__ __forceinline__ u32 f2bf_bits(float f) {
  u32 u = __float_as_uint(f);
  return (u + 0x7FFFu + ((u >> 16) & 1u)) >> 16;   // RNE
}
__device__ __forceinline__ float bf2f(u16 x) {
  return __uint_as_float(((u32)x) << 16);
}
__device__ __forceinline__ void store_c(u16* p, float v) { *p = (u16)f2bf_bits(v); }
__device__ __forceinline__ void store_c(float* p, float v) { *p = v; }

// async global->LDS, 16B per lane; LDS dest = wave-uniform base + lane*16
__device__ __forceinline__ void gload_lds16(const u16* g, u16* lds) {
  __builtin_amdgcn_global_load_lds((const __attribute__((address_space(1))) u32*)g,
                                   (__attribute__((address_space(3))) u32*)lds,
                                   16, 0, 0);
}

// ---------------- elementwise fp32 -> bf16 ----------------
__global__ __launch_bounds__(256) void convert_fp32_bf16(const float4* __restrict__ x,
                                                         uint2* __restrict__ o, int n4) {
  int i = blockIdx.x * 256 + threadIdx.x;
  if (i >= n4) return;
  float4 v = x[i];
  uint2 r;
  r.x = f2bf_bits(v.x) | (f2bf_bits(v.y) << 16);
  r.y = f2bf_bits(v.z) | (f2bf_bits(v.w) << 16);
  o[i] = r;
}

// ---------------- W (K x N) fp32 -> Wt (N x K) bf16 ----------------
__global__ __launch_bounds__(256) void transpose_conv_w(const float* __restrict__ W,
                                                        u16* __restrict__ Wt,
                                                        int Kdim, int Ndim) {
  __shared__ float tile[32][33];
  int n0 = blockIdx.x * 32, k0 = blockIdx.y * 32;
  int tx = threadIdx.x, ty = threadIdx.y;
#pragma unroll
  for (int i = 0; i < 4; i++) {
    int r = ty + i * 8;
    tile[r][tx] = W[(size_t)(k0 + r) * Ndim + n0 + tx];
  }
  __syncthreads();
#pragma unroll
  for (int i = 0; i < 4; i++) {
    int r = ty + i * 8;
    Wt[(size_t)(n0 + r) * Kdim + k0 + tx] = (u16)f2bf_bits(tile[tx][r]);
  }
}

// ---------------- V [B][S][KV][D] -> Vt [B][KV][D][S] (bf16) ----------------
__global__ __launch_bounds__(256) void transpose_v(const u16* __restrict__ V,
                                                   u16* __restrict__ Vt) {
  __shared__ u16 tile[32][33];
  int bkv = blockIdx.z;
  int b = bkv / KV_, kv = bkv % KV_;
  int s0 = blockIdx.x * 32, d0 = blockIdx.y * 32;
  int tx = threadIdx.x, ty = threadIdx.y;
#pragma unroll
  for (int i = 0; i < 4; i++) {
    int r = ty + i * 8;  // s within tile
    tile[r][tx] = V[((size_t)((b * S_ + s0 + r) * KV_ + kv)) * D_ + d0 + tx];
  }
  __syncthreads();
#pragma unroll
  for (int i = 0; i < 4; i++) {
    int r = ty + i * 8;  // d within tile
    Vt[((size_t)(b * KV_ + kv) * D_ + d0 + r) * S_ + s0 + tx] = tile[tx][r];
  }
}

// ---------------- in-place RoPE on bf16 [rows][heads][128], scale folded ----------------
__global__ __launch_bounds__(256) void rope_inplace(u16* __restrict__ X, int heads,
                                                    float scale, int total) {
  int idx = blockIdx.x * 256 + threadIdx.x;
  if (idx >= total) return;
  int d = idx & 63;
  int rem = idx >> 6;
  int h = rem % heads;
  int row = rem / heads;
  int spos = row & (S_ - 1);
  size_t base = ((size_t)row * heads + h) * D_ + d;
  float x0 = bf2f(X[base]);
  float x1 = bf2f(X[base + 64]);
  float ang = (float)spos * expf(-0.14391156831212787f * (float)d);
  float sn, cs;
  sincosf(ang, &sn, &cs);
  X[base]      = (u16)f2bf_bits((x0 * cs - x1 * sn) * scale);
  X[base + 64] = (u16)f2bf_bits((x1 * cs + x0 * sn) * scale);
}

// ---------------- bf16 GEMM: C(MxN) = A(MxK) * Bt(NxK)^T  (m97 recipe) ----------------
template <typename CT>
__device__ __forceinline__ void gemm_body(const u16* __restrict__ A, const u16* __restrict__ Bt,
                                          CT* __restrict__ C, int Kdim, int Ndim,
                                          int m0, int n0) {
  __shared__ __align__(16) u16 As[128 * 32];
  __shared__ __align__(16) u16 Bs[128 * 32];
  const int tid = threadIdx.x;
  const int lane = tid & 63;
  const int wave = tid >> 6;
  const int wm = wave >> 1, wn = wave & 1;
  const int quad = lane >> 4, lm = lane & 15;
  const int srow = tid >> 2;           // 0..63
  const int scol = (tid & 3) * 8;      // 0,8,16,24

  f32x4 zero = {0.f, 0.f, 0.f, 0.f};
  f32x4 acc[4][4];
#pragma unroll
  for (int i = 0; i < 4; i++)
#pragma unroll
    for (int j = 0; j < 4; j++) acc[i][j] = zero;

  const u16* gA = A + (size_t)(m0 + srow) * Kdim + scol;
  const u16* gB = Bt + (size_t)(n0 + srow) * Kdim + scol;
  const size_t rstep = (size_t)64 * Kdim;
  u16* ldsA0 = As + wave * 512;
  u16* ldsA1 = As + 2048 + wave * 512;
  u16* ldsB0 = Bs + wave * 512;
  u16* ldsB1 = Bs + 2048 + wave * 512;

  for (int k0 = 0; k0 < Kdim; k0 += 32) {
    gload_lds16(gA + k0, ldsA0);
    gload_lds16(gA + k0 + rstep, ldsA1);
    gload_lds16(gB + k0, ldsB0);
    gload_lds16(gB + k0 + rstep, ldsB1);
    __syncthreads();
    bf16x8 af[4], bfr[4];
#pragma unroll
    for (int mt = 0; mt < 4; mt++)
      af[mt] = *(const bf16x8*)(As + (wm * 64 + mt * 16 + lm) * 32 + quad * 8);
#pragma unroll
    for (int nt = 0; nt < 4; nt++)
      bfr[nt] = *(const bf16x8*)(Bs + (wn * 64 + nt * 16 + lm) * 32 + quad * 8);
#pragma unroll
    for (int mt = 0; mt < 4; mt++)
#pragma unroll
      for (int nt = 0; nt < 4; nt++)
        acc[mt][nt] = __builtin_amdgcn_mfma_f32_16x16x32_bf16(af[mt], bfr[nt], acc[mt][nt], 0, 0, 0);
    __syncthreads();
  }

#pragma unroll
  for (int mt = 0; mt < 4; mt++) {
    const int row = m0 + wm * 64 + mt * 16 + quad * 4;
#pragma unroll
    for (int nt = 0; nt < 4; nt++) {
      const int col = n0 + wn * 64 + nt * 16 + lm;
#pragma unroll
      for (int r = 0; r < 4; r++)
        store_c(C + (size_t)(row + r) * Ndim + col, acc[mt][nt][r]);
    }
  }
}

template <typename CT>
__global__ __launch_bounds__(256) void gemm_bt_kernel(const u16* __restrict__ A,
                                                      const u16* __restrict__ Bt,
                                                      CT* __restrict__ C, int Ndim, int Kdim) {
  gemm_body<CT>(A, Bt, C, Kdim, Ndim, blockIdx.y * 128, blockIdx.x * 128);
}

__global__ __launch_bounds__(256) void gemm_kv_kernel(const u16* __restrict__ A,
                                                      const u16* __restrict__ WkT,
                                                      const u16* __restrict__ WvT,
                                                      u16* __restrict__ Kb, u16* __restrict__ Vb) {
  int bx = blockIdx.x;
  const u16* Bt;
  u16* C;
  int n0;
  if (bx < 4) { Bt = WkT; C = Kb; n0 = bx * 128; }
  else        { Bt = WvT; C = Vb; n0 = (bx - 4) * 128; }
  gemm_body<u16>(A, Bt, C, 2048, 512, blockIdx.y * 128, n0);
}

// ---------------- causal GQA flash attention ----------------
__global__ __launch_bounds__(256) void attn_kernel(const u16* __restrict__ Q,
                                                   const u16* __restrict__ K,
                                                   const u16* __restrict__ Vt,
                                                   u16* __restrict__ O) {
  __shared__ __align__(16) u16 Qs[64 * 136];
  __shared__ __align__(16) u16 Ks[64 * 136];
  __shared__ __align__(16) u16 Vts[128 * 72];
  __shared__ __align__(16) u16 Ps[4][16 * 72];

  const int tid = threadIdx.x;
  const int lane = tid & 63;
  const int wave = tid >> 6;
  const int quad = lane >> 4, lm = lane & 15;
  const int b = blockIdx.z, h = blockIdx.y;
  const int kh = h / G_;
  const int sq0 = blockIdx.x * 64;

#pragma unroll
  for (int i = 0; i < 4; i++) {
    int c = tid + 256 * i;
    int r = c >> 4, cc = (c & 15) * 8;
    *(uint4*)(Qs + r * 136 + cc) =
        *(const uint4*)(Q + ((size_t)((b * S_ + sq0 + r) * H_ + h)) * D_ + cc);
  }

  f32x4 o[8];
  float mrow[4], lrow[4];
#pragma unroll
  for (int i = 0; i < 8; i++) o[i] = f32x4{0.f, 0.f, 0.f, 0.f};
#pragma unroll
  for (int r = 0; r < 4; r++) { mrow[r] = -__builtin_inff(); lrow[r] = 0.f; }

  const u16* Vbase = Vt + (size_t)(b * KV_ + kh) * D_ * S_;
  const int nT = (sq0 >> 6) + 1;
  for (int t = 0; t < nT; t++) {
    const int sk0 = t << 6;
    __syncthreads();
#pragma unroll
    for (int i = 0; i < 4; i++) {
      int c = tid + 256 * i;
      int r = c >> 4, cc = (c & 15) * 8;
      *(uint4*)(Ks + r * 136 + cc) =
          *(const uint4*)(K + ((size_t)((b * S_ + sk0 + r) * KV_ + kh)) * D_ + cc);
    }
#pragma unroll
    for (int i = 0; i < 4; i++) {
      int c = tid + 256 * i;
      int r = c >> 3, cc = (c & 7) * 8;
      *(uint4*)(Vts + r * 72 + cc) = *(const uint4*)(Vbase + (size_t)r * S_ + sk0 + cc);
    }
    __syncthreads();

    f32x4 sc[4];
#pragma unroll
    for (int nt = 0; nt < 4; nt++) sc[nt] = f32x4{0.f, 0.f, 0.f, 0.f};
#pragma unroll
    for (int ks = 0; ks < 4; ks++) {
      bf16x8 qa = *(const bf16x8*)(Qs + (wave * 16 + lm) * 136 + ks * 32 + quad * 8);
#pragma unroll
      for (int nt = 0; nt < 4; nt++) {
        bf16x8 kb = *(const bf16x8*)(Ks + (nt * 16 + lm) * 136 + ks * 32 + quad * 8);
        sc[nt] = __builtin_amdgcn_mfma_f32_16x16x32_bf16(qa, kb, sc[nt], 0, 0, 0);
      }
    }

    if (sk0 == sq0) {
#pragma unroll
      for (int nt = 0; nt < 4; nt++)
#pragma unroll
        for (int r = 0; r < 4; r++) {
          int qrow = wave * 16 + quad * 4 + r;
          int kcol = nt * 16 + lm;
          if (kcol > qrow) sc[nt][r] = -__builtin_inff();
        }
    }

    float tmax[4] = {-__builtin_inff(), -__builtin_inff(), -__builtin_inff(), -__builtin_inff()};
#pragma unroll
    for (int nt = 0; nt < 4; nt++)
#pragma unroll
      for (int r = 0; r < 4; r++) tmax[r] = fmaxf(tmax[r], sc[nt][r]);
#pragma unroll
    for (int r = 0; r < 4; r++) {
      float v = tmax[r];
      v = fmaxf(v, __shfl_xor(v, 1));
      v = fmaxf(v, __shfl_xor(v, 2));
      v = fmaxf(v, __shfl_xor(v, 4));
      v = fmaxf(v, __shfl_xor(v, 8));
      tmax[r] = v;
    }
    float alpha[4];
#pragma unroll
    for (int r = 0; r < 4; r++) {
      float mn = fmaxf(mrow[r], tmax[r]);
      alpha[r] = __expf(mrow[r] - mn);
      mrow[r] = mn;
    }
    float rsum[4] = {0.f, 0.f, 0.f, 0.f};
#pragma unroll
    for (int nt = 0; nt < 4; nt++)
#pragma unroll
      for (int r = 0; r < 4; r++) {
        float p = __expf(sc[nt][r] - mrow[r]);
        sc[nt][r] = p;
        rsum[r] += p;
      }
#pragma unroll
    for (int r = 0; r < 4; r++) {
      float v = rsum[r];
      v += __shfl_xor(v, 1);
      v += __shfl_xor(v, 2);
      v += __shfl_xor(v, 4);
      v += __shfl_xor(v, 8);
      lrow[r] = lrow[r] * alpha[r] + v;
    }

    u16* pw = &Ps[wave][0];
#pragma unroll
    for (int nt = 0; nt < 4; nt++)
#pragma unroll
      for (int r = 0; r < 4; r++)
        pw[(quad * 4 + r) * 72 + nt * 16 + lm] = (u16)f2bf_bits(sc[nt][r]);
    __syncthreads();

#pragma unroll
    for (int d8 = 0; d8 < 8; d8++)
#pragma unroll
      for (int r = 0; r < 4; r++) o[d8][r] *= alpha[r];
#pragma unroll
    for (int ks = 0; ks < 2; ks++) {
      bf16x8 pa = *(const bf16x8*)(pw + lm * 72 + ks * 32 + quad * 8);
#pragma unroll
      for (int d8 = 0; d8 < 8; d8++) {
        bf16x8 vb = *(const bf16x8*)(Vts + (d8 * 16 + lm) * 72 + ks * 32 + quad * 8);
        o[d8] = __builtin_amdgcn_mfma_f32_16x16x32_bf16(pa, vb, o[d8], 0, 0, 0);
      }
    }
  }

#pragma unroll
  for (int d8 = 0; d8 < 8; d8++)
#pragma unroll
    for (int r = 0; r < 4; r++) {
      int srow = sq0 + wave * 16 + quad * 4 + r;
      O[((size_t)((b * S_ + srow) * H_ + h)) * D_ + d8 * 16 + lm] =
          (u16)f2bf_bits(o[d8][r] / lrow[r]);
    }
}

extern "C" void kernel_launch(void* const* d_in, const int* in_sizes, int n_in,
                              void* d_out, int out_size, void* d_ws, size_t ws_size,
                              hipStream_t stream) {
  const float* x  = (const float*)d_in[0];
  const float* Wq = (const float*)d_in[1];
  const float* Wk = (const float*)d_in[2];
  const float* Wv = (const float*)d_in[3];
  const float* Wo = (const float*)d_in[4];
  float* out = (float*)d_out;
  char* ws = (char*)d_ws;
  u16* Xb  = (u16*)(ws);
  u16* WqT = (u16*)(ws + (16ull << 20));
  u16* WkT = (u16*)(ws + (24ull << 20));
  u16* WvT = (u16*)(ws + (26ull << 20));
  u16* WoT = (u16*)(ws + (28ull << 20));
  u16* Qb  = (u16*)(ws + (36ull << 20));
  u16* Kb  = (u16*)(ws + (52ull << 20));
  u16* Vb  = (u16*)(ws + (56ull << 20));
  u16* Vt  = (u16*)(ws + (60ull << 20));
  u16* Ob  = (u16*)(ws + (64ull << 20));

  dim3 tb32(32, 8);

  convert_fp32_bf16<<<dim3(M_ * E_ / 4 / 256), 256, 0, stream>>>((const float4*)x, (uint2*)Xb, M_ * E_ / 4);
  transpose_conv_w<<<dim3(2048 / 32, 2048 / 32), tb32, 0, stream>>>(Wq, WqT, E_, H_ * D_);
  transpose_conv_w<<<dim3(512 / 32, 2048 / 32), tb32, 0, stream>>>(Wk, WkT, E_, KV_ * D_);
  transpose_conv_w<<<dim3(512 / 32, 2048 / 32), tb32, 0, stream>>>(Wv, WvT, E_, KV_ * D_);
  transpose_conv_w<<<dim3(2048 / 32, 2048 / 32), tb32, 0, stream>>>(Wo, WoT, E_, E_);

  gemm_bt_kernel<u16><<<dim3(2048 / 128, M_ / 128), 256, 0, stream>>>(Xb, WqT, Qb, 2048, 2048);
  gemm_kv_kernel<<<dim3(8, M_ / 128), 256, 0, stream>>>(Xb, WkT, WvT, Kb, Vb);

  rope_inplace<<<dim3(M_ * H_ * 64 / 256), 256, 0, stream>>>(Qb, H_, 0.08838834764831845f, M_ * H_ * 64);
  rope_inplace<<<dim3(M_ * KV_ * 64 / 256), 256, 0, stream>>>(Kb, KV_, 1.0f, M_ * KV_ * 64);

  transpose_v<<<dim3(S_ / 32, D_ / 32, B_ * KV_), tb32, 0, stream>>>(Vb, Vt);

  attn_kernel<<<dim3(S_ / 64, H_, B_), 256, 0, stream>>>(Qb, Kb, Vt, Ob);

  gemm_bt_kernel<float><<<dim3(2048 / 128, M_ / 128), 256, 0, stream>>>(Ob, WoT, out, 2048, 2048);
}